// Round 5
// baseline (583.318 us; speedup 1.0000x reference)
//
#include <hip/hip_runtime.h>
#include <hip/hip_bf16.h>
#include <math.h>

#define N 8192
#define D 1024
#define TILE 128
#define NTILES (N / TILE)                 // 64
#define NBLOCKS (NTILES * (NTILES + 1) / 2)  // 2080 lower-tri tiles

typedef float f32x4 __attribute__((ext_vector_type(4)));
typedef int   i32x4 __attribute__((ext_vector_type(4)));
typedef int   i32x8 __attribute__((ext_vector_type(8)));

// exp(sim/T) = exp2(sim/(T*ln2)); fold sqrt(1/(T*ln2)) into the normalized
// embeddings so the accumulator is the exp2 argument directly.
#define POST_SCALE 4.5398124f

// ---------------------------------------------------------------------------
// Kernel 1: L2-normalize rows, scale, cast to fp8 e4m3 (OCP). Also zeroes
// sumExp/posSum (blocks 0..63 cover 2N = 16384 floats).
// ---------------------------------------------------------------------------
__global__ __launch_bounds__(256) void norm_cast(const float* __restrict__ in,
                                                 unsigned char* __restrict__ out,
                                                 float* __restrict__ sums) {
    const int row = blockIdx.x;
    const int tid = threadIdx.x;
    if (row < 64) sums[row * 256 + tid] = 0.f;
    const float4 v = ((const float4*)(in + (size_t)row * D))[tid];
    float ss = v.x * v.x + v.y * v.y + v.z * v.z + v.w * v.w;
    #pragma unroll
    for (int off = 32; off >= 1; off >>= 1) ss += __shfl_xor(ss, off, 64);
    __shared__ float red[4];
    const int wave = tid >> 6, lane = tid & 63;
    if (lane == 0) red[wave] = ss;
    __syncthreads();
    const float tot = red[0] + red[1] + red[2] + red[3];
    const float scale = POST_SCALE / fmaxf(sqrtf(tot), 1e-12f);
    // pack 4 floats -> 4 fp8 bytes (v_cvt_pk_fp8_f32: s0->byte0, s1->byte1)
    int w = __builtin_amdgcn_cvt_pk_fp8_f32(v.x * scale, v.y * scale, 0, false);
    w = __builtin_amdgcn_cvt_pk_fp8_f32(v.z * scale, v.w * scale, w, true);
    ((int*)(out + (size_t)row * D))[tid] = w;
}

// ---------------------------------------------------------------------------
// Kernel 2: fused symmetric GEMM in MX-fp8, mfma_scale 16x16x128 (scale=1.0:
// E8M0 0x7F in every byte, opsel-proof). BK=128 -> 8 K-iters. Tile rows are
// 128 B = 8 16B-units; unit l of row r stored at l^(r&7) (staging permutes
// the global source inside the 128B row -> still coalesced, LDS dest stays
// wave-uniform-linear). Frag reads: 2 lanes/unit = 2-way = free (m136).
// ---------------------------------------------------------------------------
__global__ __launch_bounds__(256, 4) void gemm_fused(
        const unsigned char* __restrict__ E, const int* __restrict__ labels,
        float* __restrict__ sumExp, float* __restrict__ posSum) {
    __shared__ unsigned char smem[2 * TILE * 128];   // A: [0,16K), B: [16K,32K)
    __shared__ int labR[TILE], labC[TILE];

    // triangular decode: b -> (ti >= tj)
    const int b = blockIdx.x;
    int ti = (int)((sqrtf(8.0f * (float)b + 1.0f) - 1.0f) * 0.5f);
    while ((ti + 1) * (ti + 2) / 2 <= b) ++ti;
    while (ti * (ti + 1) / 2 > b) --ti;
    const int tj = b - ti * (ti + 1) / 2;
    const bool isDiag = (ti == tj);

    const int tid     = threadIdx.x;
    const int wave    = tid >> 6;
    const int lane    = tid & 63;
    const int q       = lane >> 4;
    const int lr      = lane & 15;
    const int waveRow = wave >> 1;
    const int waveCol = wave & 1;
    const int rowStart = ti * TILE;
    const int colStart = tj * TILE;

    if (tid < TILE) labR[tid] = labels[rowStart + tid];
    else            labC[tid - TILE] = labels[colStart + (tid - TILE)];

    f32x4 acc[4][4];
    #pragma unroll
    for (int i = 0; i < 4; ++i)
        #pragma unroll
        for (int j = 0; j < 4; ++j)
            acc[i][j] = {0.f, 0.f, 0.f, 0.f};

    // Staging: pass p covers rows p*32..p*32+31 (8 units/row). Thread tid
    // covers row r0 = tid>>3 (+p*32), logical unit (tid&7)^(r0&7).
    const int r0 = tid >> 3;
    const int lc = (tid & 7) ^ (r0 & 7);
    const unsigned char* gaBase = E + (size_t)(rowStart + r0) * D + lc * 16;
    const unsigned char* gbBase = E + (size_t)(colStart + r0) * D + lc * 16;

    // Frag-read addressing: row = waveGrp*64 + lr (+16*ri via imm, stride
    // 2048 B); logical units 2q, 2q+1 -> physical (2q)^(lr&7), ^1.
    const unsigned x     = (unsigned)(lr & 7);
    const unsigned aBase = (unsigned)((waveRow * 64 + lr) * 128);
    const unsigned bBase = (unsigned)(16384 + (waveCol * 64 + lr) * 128);
    const unsigned u0    = ((2u * q) ^ x) * 16;   // u1 = u0 ^ 16

    for (int it = 0; it < 8; ++it) {
        const unsigned kb = (unsigned)it * 128;
        #pragma unroll
        for (int p = 0; p < 4; ++p) {
            const unsigned char* ga = gaBase + kb + p * 32 * D;
            const unsigned char* gb = gbBase + kb + p * 32 * D;
            char* la = (char*)smem + (p * 256 + wave * 64) * 16;
            char* lb = (char*)smem + 16384 + (p * 256 + wave * 64) * 16;
            __builtin_amdgcn_global_load_lds(
                (const __attribute__((address_space(1))) void*)ga,
                (__attribute__((address_space(3))) void*)la, 16, 0, 0);
            __builtin_amdgcn_global_load_lds(
                (const __attribute__((address_space(1))) void*)gb,
                (__attribute__((address_space(3))) void*)lb, 16, 0, 0);
        }
        __syncthreads();

        i32x8 af[4];
        #pragma unroll
        for (int ri = 0; ri < 4; ++ri) {
            const i32x4 lo = *(const i32x4*)(smem + aBase + ri * 2048 + u0);
            const i32x4 hi = *(const i32x4*)(smem + aBase + ri * 2048 + (u0 ^ 16));
            af[ri] = __builtin_shufflevector(lo, hi, 0, 1, 2, 3, 4, 5, 6, 7);
        }
        #pragma unroll
        for (int ci = 0; ci < 4; ++ci) {   // B per-ci: keeps VGPR live-set low
            const i32x4 lo = *(const i32x4*)(smem + bBase + ci * 2048 + u0);
            const i32x4 hi = *(const i32x4*)(smem + bBase + ci * 2048 + (u0 ^ 16));
            const i32x8 bf = __builtin_shufflevector(lo, hi, 0, 1, 2, 3, 4, 5, 6, 7);
            #pragma unroll
            for (int ri = 0; ri < 4; ++ri)
                acc[ri][ci] = __builtin_amdgcn_mfma_scale_f32_16x16x128_f8f6f4(
                    af[ri], bf, acc[ri][ci], 0, 0,       // cbsz=fp8, blgp=fp8
                    0, 0x7F7F7F7F, 0, 0x7F7F7F7F);       // scales = 1.0
        }
        __syncthreads();
    }

    // ---- epilogue: exp2(acc) -> masked row sums (+ col sums off-diagonal) ----
    // C/D layout: col = lane&15, row = q*4 + e (shape-determined; m89/m121-128).
    float colAll[4] = {0.f, 0.f, 0.f, 0.f};
    float colPos[4] = {0.f, 0.f, 0.f, 0.f};
    #pragma unroll
    for (int ri = 0; ri < 4; ++ri) {
        #pragma unroll
        for (int e = 0; e < 4; ++e) {
            const int rloc = waveRow * 64 + ri * 16 + q * 4 + e;
            const int gi   = rowStart + rloc;
            const int li   = labR[rloc];
            float s_all = 0.f, s_pos = 0.f;
            #pragma unroll
            for (int ci = 0; ci < 4; ++ci) {
                const int cloc = waveCol * 64 + ci * 16 + lr;
                const int gj   = colStart + cloc;
#if __has_builtin(__builtin_amdgcn_exp2f)
                const float v = __builtin_amdgcn_exp2f(acc[ri][ci][e]);
#else
                const float v = exp2f(acc[ri][ci][e]);
#endif
                const bool same = (labC[cloc] == li);
                const float vp  = same ? v : 0.f;
                s_all += v;
                if (gi != gj) s_pos += vp;
                if (!isDiag) {          // wave-uniform branch
                    colAll[ci] += v;
                    colPos[ci] += vp;
                }
            }
            #pragma unroll
            for (int off = 1; off < 16; off <<= 1) {
                s_all += __shfl_xor(s_all, off, 64);
                s_pos += __shfl_xor(s_pos, off, 64);
            }
            if (lr == 0) {
                atomicAdd(&sumExp[gi], s_all);
                atomicAdd(&posSum[gi], s_pos);
            }
        }
    }
    if (!isDiag) {
        #pragma unroll
        for (int ci = 0; ci < 4; ++ci) {
            float a = colAll[ci], p = colPos[ci];
            a += __shfl_xor(a, 16, 64);  a += __shfl_xor(a, 32, 64);
            p += __shfl_xor(p, 16, 64);  p += __shfl_xor(p, 32, 64);
            if (q == 0) {
                const int gj = colStart + waveCol * 64 + ci * 16 + lr;
                atomicAdd(&sumExp[gj], a);
                atomicAdd(&posSum[gj], p);
            }
        }
    }
}

// ---------------------------------------------------------------------------
// Kernel 3: loss_i = log(sumExp_i / posSum_i); out = mean(loss).
// ---------------------------------------------------------------------------
__global__ __launch_bounds__(1024) void finalize(const float* __restrict__ sumExp,
                                                 const float* __restrict__ posSum,
                                                 float* __restrict__ out) {
    const int tid = threadIdx.x;
    float s = 0.f;
    #pragma unroll
    for (int i = tid; i < N; i += 1024)
        s += __logf(sumExp[i] / posSum[i]);
    #pragma unroll
    for (int off = 32; off >= 1; off >>= 1) s += __shfl_xor(s, off, 64);
    __shared__ float red[16];
    if ((tid & 63) == 0) red[tid >> 6] = s;
    __syncthreads();
    if (tid == 0) {
        float t = 0.f;
        #pragma unroll
        for (int i = 0; i < 16; ++i) t += red[i];
        out[0] = t / (float)N;
    }
}

extern "C" void kernel_launch(void* const* d_in, const int* in_sizes, int n_in,
                              void* d_out, int out_size, void* d_ws, size_t ws_size,
                              hipStream_t stream) {
    const float* emb    = (const float*)d_in[0];
    const int*   labels = (const int*)d_in[1];
    float* out = (float*)d_out;

    // ws layout: [sumExp: N floats][posSum: N floats][EN: N*D fp8]
    float*         sumExp = (float*)d_ws;
    float*         posSum = sumExp + N;
    unsigned char* EN     = (unsigned char*)((char*)d_ws + (size_t)2 * N * sizeof(float));

    norm_cast<<<N, 256, 0, stream>>>(emb, EN, sumExp);

    gemm_fused<<<NBLOCKS, 256, 0, stream>>>(EN, labels, sumExp, posSum);

    finalize<<<1, 1024, 0, stream>>>(sumExp, posSum, out);
}

// Round 6
// 502.078 us; speedup vs baseline: 1.1618x; 1.1618x over previous
//
#include <hip/hip_runtime.h>
#include <hip/hip_bf16.h>
#include <math.h>

#define N 8192
#define D 1024
#define TILE 128
#define NTILES (N / TILE)                 // 64
#define NBLOCKS (NTILES * (NTILES + 1) / 2)  // 2080 lower-tri tiles

typedef float f32x4 __attribute__((ext_vector_type(4)));
typedef int   i32x4 __attribute__((ext_vector_type(4)));
typedef int   i32x8 __attribute__((ext_vector_type(8)));

// exp(sim/T) = exp2(sim/(T*ln2)); fold sqrt(1/(T*ln2)) into the normalized
// embeddings so the accumulator is the exp2 argument directly.
#define POST_SCALE 4.5398124f

// ---------------------------------------------------------------------------
// Kernel 1: L2-normalize rows, scale, cast to fp8 e4m3 (OCP). Also zeroes
// sumExp/posSum (blocks 0..63 cover 2N = 16384 floats).
// ---------------------------------------------------------------------------
__global__ __launch_bounds__(256) void norm_cast(const float* __restrict__ in,
                                                 unsigned char* __restrict__ out,
                                                 float* __restrict__ sums) {
    const int row = blockIdx.x;
    const int tid = threadIdx.x;
    if (row < 64) sums[row * 256 + tid] = 0.f;
    const float4 v = ((const float4*)(in + (size_t)row * D))[tid];
    float ss = v.x * v.x + v.y * v.y + v.z * v.z + v.w * v.w;
    #pragma unroll
    for (int off = 32; off >= 1; off >>= 1) ss += __shfl_xor(ss, off, 64);
    __shared__ float red[4];
    const int wave = tid >> 6, lane = tid & 63;
    if (lane == 0) red[wave] = ss;
    __syncthreads();
    const float tot = red[0] + red[1] + red[2] + red[3];
    const float scale = POST_SCALE / fmaxf(sqrtf(tot), 1e-12f);
    // pack 4 floats -> 4 fp8 bytes (v_cvt_pk_fp8_f32: s0->byte0, s1->byte1)
    int w = __builtin_amdgcn_cvt_pk_fp8_f32(v.x * scale, v.y * scale, 0, false);
    w = __builtin_amdgcn_cvt_pk_fp8_f32(v.z * scale, v.w * scale, w, true);
    ((int*)(out + (size_t)row * D))[tid] = w;
}

// ---------------------------------------------------------------------------
// Kernel 2: fused symmetric GEMM in MX-fp8, mfma_scale 16x16x128 (scale=1.0:
// E8M0 0x7F, uniform). BK=128 -> 8 K-iters, 32 KB LDS staging per iter.
// Swizzle: 16B unit l of row r stored at l^(r&7); staging permutes the
// GLOBAL source within the 128B row (coalesced, LDS dest wave-uniform).
// __launch_bounds__(256,3): ~170-reg budget. R5's (256,4) cap (128 regs)
// forced the K-loop accumulators to spill to scratch (854 MB WRITE_SIZE,
// 3.4x regression) -- fp8 frags are i32x8 (8 VGPRs), twice bf16's.
// ---------------------------------------------------------------------------
__global__ __launch_bounds__(256, 3) void gemm_fused(
        const unsigned char* __restrict__ E, const int* __restrict__ labels,
        float* __restrict__ sumExp, float* __restrict__ posSum) {
    __shared__ unsigned char smem[2 * TILE * 128];   // A: [0,16K), B: [16K,32K)
    __shared__ int labR[TILE], labC[TILE];

    // triangular decode: b -> (ti >= tj)
    const int b = blockIdx.x;
    int ti = (int)((sqrtf(8.0f * (float)b + 1.0f) - 1.0f) * 0.5f);
    while ((ti + 1) * (ti + 2) / 2 <= b) ++ti;
    while (ti * (ti + 1) / 2 > b) --ti;
    const int tj = b - ti * (ti + 1) / 2;
    const bool isDiag = (ti == tj);

    const int tid     = threadIdx.x;
    const int wave    = tid >> 6;
    const int lane    = tid & 63;
    const int q       = lane >> 4;
    const int lr      = lane & 15;
    const int waveRow = wave >> 1;
    const int waveCol = wave & 1;
    const int rowStart = ti * TILE;
    const int colStart = tj * TILE;

    if (tid < TILE) labR[tid] = labels[rowStart + tid];
    else            labC[tid - TILE] = labels[colStart + (tid - TILE)];

    f32x4 acc[4][4];
    #pragma unroll
    for (int i = 0; i < 4; ++i)
        #pragma unroll
        for (int j = 0; j < 4; ++j)
            acc[i][j] = {0.f, 0.f, 0.f, 0.f};

    // Staging: pass p covers rows p*32..p*32+31 (8 units/row). Thread tid
    // covers row r0 = tid>>3 (+p*32), logical unit (tid&7)^(r0&7).
    const int r0 = tid >> 3;
    const int lc = (tid & 7) ^ (r0 & 7);
    const unsigned char* gaBase = E + (size_t)(rowStart + r0) * D + lc * 16;
    const unsigned char* gbBase = E + (size_t)(colStart + r0) * D + lc * 16;

    // Frag-read addressing: row = waveGrp*64 + lr (+16*ri via imm, stride
    // 2048 B); logical units 2q, 2q+1 -> physical (2q)^(lr&7), ^1.
    const unsigned x     = (unsigned)(lr & 7);
    const unsigned aBase = (unsigned)((waveRow * 64 + lr) * 128);
    const unsigned bBase = (unsigned)(16384 + (waveCol * 64 + lr) * 128);
    const unsigned u0    = ((2u * q) ^ x) * 16;   // u1 = u0 ^ 16

    for (int it = 0; it < 8; ++it) {
        const unsigned kb = (unsigned)it * 128;
        #pragma unroll
        for (int p = 0; p < 4; ++p) {
            const unsigned char* ga = gaBase + kb + p * 32 * D;
            const unsigned char* gb = gbBase + kb + p * 32 * D;
            char* la = (char*)smem + (p * 256 + wave * 64) * 16;
            char* lb = (char*)smem + 16384 + (p * 256 + wave * 64) * 16;
            __builtin_amdgcn_global_load_lds(
                (const __attribute__((address_space(1))) void*)ga,
                (__attribute__((address_space(3))) void*)la, 16, 0, 0);
            __builtin_amdgcn_global_load_lds(
                (const __attribute__((address_space(1))) void*)gb,
                (__attribute__((address_space(3))) void*)lb, 16, 0, 0);
        }
        __syncthreads();

        i32x8 af[4];
        #pragma unroll
        for (int ri = 0; ri < 4; ++ri) {
            const i32x4 lo = *(const i32x4*)(smem + aBase + ri * 2048 + u0);
            const i32x4 hi = *(const i32x4*)(smem + aBase + ri * 2048 + (u0 ^ 16));
            af[ri] = __builtin_shufflevector(lo, hi, 0, 1, 2, 3, 4, 5, 6, 7);
        }
        #pragma unroll
        for (int ci = 0; ci < 4; ++ci) {   // B per-ci: keeps VGPR live-set low
            const i32x4 lo = *(const i32x4*)(smem + bBase + ci * 2048 + u0);
            const i32x4 hi = *(const i32x4*)(smem + bBase + ci * 2048 + (u0 ^ 16));
            const i32x8 bf = __builtin_shufflevector(lo, hi, 0, 1, 2, 3, 4, 5, 6, 7);
            #pragma unroll
            for (int ri = 0; ri < 4; ++ri)
                acc[ri][ci] = __builtin_amdgcn_mfma_scale_f32_16x16x128_f8f6f4(
                    af[ri], bf, acc[ri][ci], 0, 0,       // cbsz=fp8, blgp=fp8
                    0, 0x7F7F7F7F, 0, 0x7F7F7F7F);       // scales = 1.0
        }
        __syncthreads();
    }

    // ---- epilogue: exp2(acc) -> masked row sums (+ col sums off-diagonal) ----
    // C/D layout: col = lane&15, row = q*4 + e (shape-determined; m89/m121-128).
    float colAll[4] = {0.f, 0.f, 0.f, 0.f};
    float colPos[4] = {0.f, 0.f, 0.f, 0.f};
    #pragma unroll
    for (int ri = 0; ri < 4; ++ri) {
        #pragma unroll
        for (int e = 0; e < 4; ++e) {
            const int rloc = waveRow * 64 + ri * 16 + q * 4 + e;
            const int gi   = rowStart + rloc;
            const int li   = labR[rloc];
            float s_all = 0.f, s_pos = 0.f;
            #pragma unroll
            for (int ci = 0; ci < 4; ++ci) {
                const int cloc = waveCol * 64 + ci * 16 + lr;
                const int gj   = colStart + cloc;
#if __has_builtin(__builtin_amdgcn_exp2f)
                const float v = __builtin_amdgcn_exp2f(acc[ri][ci][e]);
#else
                const float v = exp2f(acc[ri][ci][e]);
#endif
                const bool same = (labC[cloc] == li);
                const float vp  = same ? v : 0.f;
                s_all += v;
                if (gi != gj) s_pos += vp;
                if (!isDiag) {          // wave-uniform branch
                    colAll[ci] += v;
                    colPos[ci] += vp;
                }
            }
            #pragma unroll
            for (int off = 1; off < 16; off <<= 1) {
                s_all += __shfl_xor(s_all, off, 64);
                s_pos += __shfl_xor(s_pos, off, 64);
            }
            if (lr == 0) {
                atomicAdd(&sumExp[gi], s_all);
                atomicAdd(&posSum[gi], s_pos);
            }
        }
    }
    if (!isDiag) {
        #pragma unroll
        for (int ci = 0; ci < 4; ++ci) {
            float a = colAll[ci], p = colPos[ci];
            a += __shfl_xor(a, 16, 64);  a += __shfl_xor(a, 32, 64);
            p += __shfl_xor(p, 16, 64);  p += __shfl_xor(p, 32, 64);
            if (q == 0) {
                const int gj = colStart + waveCol * 64 + ci * 16 + lr;
                atomicAdd(&sumExp[gj], a);
                atomicAdd(&posSum[gj], p);
            }
        }
    }
}

// ---------------------------------------------------------------------------
// Kernel 3: loss_i = log(sumExp_i / posSum_i); out = mean(loss).
// ---------------------------------------------------------------------------
__global__ __launch_bounds__(1024) void finalize(const float* __restrict__ sumExp,
                                                 const float* __restrict__ posSum,
                                                 float* __restrict__ out) {
    const int tid = threadIdx.x;
    float s = 0.f;
    #pragma unroll
    for (int i = tid; i < N; i += 1024)
        s += __logf(sumExp[i] / posSum[i]);
    #pragma unroll
    for (int off = 32; off >= 1; off >>= 1) s += __shfl_xor(s, off, 64);
    __shared__ float red[16];
    if ((tid & 63) == 0) red[tid >> 6] = s;
    __syncthreads();
    if (tid == 0) {
        float t = 0.f;
        #pragma unroll
        for (int i = 0; i < 16; ++i) t += red[i];
        out[0] = t / (float)N;
    }
}

extern "C" void kernel_launch(void* const* d_in, const int* in_sizes, int n_in,
                              void* d_out, int out_size, void* d_ws, size_t ws_size,
                              hipStream_t stream) {
    const float* emb    = (const float*)d_in[0];
    const int*   labels = (const int*)d_in[1];
    float* out = (float*)d_out;

    // ws layout: [sumExp: N floats][posSum: N floats][EN: N*D fp8]
    float*         sumExp = (float*)d_ws;
    float*         posSum = sumExp + N;
    unsigned char* EN     = (unsigned char*)((char*)d_ws + (size_t)2 * N * sizeof(float));

    norm_cast<<<N, 256, 0, stream>>>(emb, EN, sumExp);

    gemm_fused<<<NBLOCKS, 256, 0, stream>>>(EN, labels, sumExp, posSum);

    finalize<<<1, 1024, 0, stream>>>(sumExp, posSum, out);
}